// Round 7
// baseline (159.769 us; speedup 1.0000x reference)
//
#include <hip/hip_runtime.h>

// WindowOverlapProcessor — single-wave self-contained blocks, async staging.
//
// R0-R6: five read-pipeline structures all pin at ~3.2-3.4 TB/s effective
// (fills sustain 6.9 TB/s write on the same runs). Last untested residual:
// R6 couples 4 waves per barrier (slowest-wave drain) at 3 block-pipes/CU.
// Here block = ONE wave owning a 2-row x 128-col output slice:
//   - stages exactly its own data: rows r0,r0+1 of 34 half-window chunks
//     = 34 pieces x 384 B = 13 KB, via global_load_lds width-16
//     (fire-and-forget, no VGPR writeback)
//   - pad-25 piece packing for bank-conflict-free ds_read, realized by
//     permuting the per-lane GLOBAL source (LDS dest stays linear)
//   - __syncthreads on a 1-wave block = pure self-vmcnt drain
//   - 14.3 KB LDS -> 11 independent pipelines/CU (vs 3 coupled)
//   - row-pair siblings of a tile land on the same XCD (d%8) within 32
//     dispatches -> 64-B-offset piece edges are L2-shared (no overfetch)
// Traffic unchanged: ~104 MB dense full-sector read + 25.2 MB write.

#define OH 512
#define OW 512
#define NB 8
#define NC 3
#define HWIN 63
#define NWIN (HWIN * HWIN)
#define PLANE (OH * OW)

typedef float f4 __attribute__((ext_vector_type(4)));
typedef unsigned int u32;

// g[d] = exp(-(d-7.5)^2/32)/S, S = 9.5759374 (self-consistent normalize)
__device__ __forceinline__ float gblend(int d) {
    const float x = (float)d - 7.5f;
    return __expf(-(x * x) * 0.03125f) * 0.1044284f;
}

__device__ __forceinline__ void async_ld16(const f4* gsrc, f4* ldst) {
    __builtin_amdgcn_global_load_lds(
        (const __attribute__((address_space(1))) u32*)gsrc,
        (__attribute__((address_space(3))) u32*)ldst, 16, 0, 0);
}

__global__ __launch_bounds__(64) void window_overlap_kernel(
    const float* __restrict__ win, float* __restrict__ out) {
    __shared__ f4 lds[896];  // 34 pieces x 25-f4 padded stride (+tail)

    const int bi = blockIdx.x;
    // decomposition: rp-siblings (same t,q,b; rp=0..3) sit at d, d+8, d+16,
    // d+24 -> same XCD under round-robin, temporally adjacent.
    const int rp = (bi >> 3) & 3;                // row pair: rows 2rp, 2rp+1
    const int u = (bi & 7) | ((bi >> 5) << 3);   // [0, 2048)
    const int t = u & 3;                         // col tile [128t, 128t+128)
    const int q = (u >> 2) & 63;                 // band: rows [8q, 8q+8)
    const int b = u >> 8;
    const int r0 = rp << 1;

    const int qL = min(q, 62);     // low-half source window-row
    const int qH = max(q - 1, 0);  // high-half source window-row
    const int bOff = b * NWIN;
    const int lane = threadIdx.x;  // 0..63

    // ---- stage: pieces = rows r0,r0+1 (24 f4 contiguous) of each of 34
    // chunks; logical piece k, offset e lives at LDS slot k*25+e (pad-25).
    // Dest linear (global_load_lds), permutation on the source address. ----
    const f4* __restrict__ w4 = (const f4*)win;
#pragma unroll
    for (int i = 0; i < 14; ++i) {
        const int P = i * 64 + lane;   // padded LDS f4 slot this lane fills
        int k = P / 25;                // piece (magic-div)
        int e = P - k * 25;
        k = min(k, 33);                // tail slots: harmless dup reads
        e = min(e, 23);                // pad slot e==24: dup read
        const int hi = (k >= 17) ? 1 : 0;
        const int kk = k - hi * 17;    // window slot 0..16
        const int jj = min(max(16 * t - 1 + kk, 0), HWIN - 1);
        const int qr = hi ? qH : qL;
        const int gidx = (bOff + qr * HWIN + jj) * 192 + hi * 96 + r0 * 12 + e;
        async_ld16(w4 + gidx, &lds[i * 64]);  // dest wave-uniform + lane*16
    }
    __syncthreads();  // 1 wave: pure vmcnt/lgkm drain of OUR loads only

    // ---- compute: lane -> (row rl, 4-px col group) of the 2x128 slice ----
    const int rl = lane >> 5;            // 0/1
    const int w4p = (lane & 31) << 2;    // local col 0..124
    const int jl = w4p >> 3;             // local window 0..15
    const int c0 = w4p & 7;              // 0 or 4
    const int jg = 16 * t + jl;
    const float fB = (jg <= HWIN - 1) ? 1.0f : 0.0f;  // jg==63: invalid
    const float fA = (jg >= 1) ? 1.0f : 0.0f;         // jg==0:  invalid
    const int r = r0 + rl;                            // row within band
    const float wT = (q <= 62) ? gblend(r) : 0.0f;    // low-half row weight
    const float wB = (q >= 1) ? gblend(r + 8) : 0.0f; // high-half row weight

    // padded LDS base: piece*25 + rl*12 (+6 for cols 8..15) + s0
    const int s0 = (c0 >> 2) * 3;        // 0 or 3
    const int ro = rl * 12;
    const int FLoB = (jl + 1) * 25 + ro + s0;
    const int FLoA = jl * 25 + ro + 6 + s0;
    const int FHiB = (18 + jl) * 25 + ro + s0;
    const int FHiA = (17 + jl) * 25 + ro + 6 + s0;

    f4 lb[3], la[3], hb[3], ha[3];
#pragma unroll
    for (int k = 0; k < 3; ++k) {
        lb[k] = lds[FLoB + k];
        la[k] = lds[FLoA + k];
        hb[k] = lds[FHiB + k];
        ha[k] = lds[FHiA + k];
    }

    // normalized horizontal weights for the 4 px (literal-vector select)
    const f4 gB = c0 ? (f4){0.0712141f, 0.0859006f, 0.0973380f, 0.1036157f}
                     : (f4){0.0180058f, 0.0278880f, 0.0405766f, 0.0554615f};
    const f4 gA = c0 ? (f4){0.0554615f, 0.0405766f, 0.0278880f, 0.0180058f}
                     : (f4){0.1036157f, 0.0973380f, 0.0859006f, 0.0712141f};

    f4 o[NC];
#pragma unroll
    for (int m = 0; m < 4; ++m) {
        const float wBc = fB * gB[m];
        const float wAc = fA * gA[m];
        const float rn = __builtin_amdgcn_rcpf((wT + wB) * (wAc + wBc) + 1e-8f);
#pragma unroll
        for (int ch = 0; ch < NC; ++ch) {
            const int f = 3 * m + ch;
            const float v = wT * (wAc * la[f >> 2][f & 3] + wBc * lb[f >> 2][f & 3]) +
                            wB * (wAc * ha[f >> 2][f & 3] + wBc * hb[f >> 2][f & 3]);
            o[ch][m] = v * rn;
        }
    }

    const int p = b * (NC * PLANE) + (8 * q + r) * OW + 128 * t + w4p;
    __builtin_nontemporal_store(o[0], (f4*)&out[p]);
    __builtin_nontemporal_store(o[1], (f4*)&out[p + PLANE]);
    __builtin_nontemporal_store(o[2], (f4*)&out[p + 2 * PLANE]);
}

extern "C" void kernel_launch(void* const* d_in, const int* in_sizes, int n_in,
                              void* d_out, int out_size, void* d_ws, size_t ws_size,
                              hipStream_t stream) {
    const float* windows = (const float*)d_in[0];
    float* out = (float*)d_out;
    // 4 row-pairs x 4 col-tiles x 64 bands x 8 images = 8192 single-wave blocks
    window_overlap_kernel<<<8192, 64, 0, stream>>>(windows, out);
}